// Round 11
// baseline (487.684 us; speedup 1.0000x reference)
//
#include <hip/hip_runtime.h>

typedef short short8v __attribute__((ext_vector_type(8)));
typedef float f32x4  __attribute__((ext_vector_type(4)));

#define NP    81
#define P2    83
#define Y2    66
#define X2    66
#define PIX2  (Y2*X2)             // 4356 pixels per padded (y,x) plane
#define SLABE ((long)P2*PIX2*16)  // bf16 elems per (b,d) slab = 5,784,768

// conv tile geometry: 3p x 3y out, [5 pp][5 yy][66 xx][16 gi] staged
#define TROW  330                 // 5*66 pixels per pp-plane in tile
#define TCHUNK 3300               // 5*330 pixels * 2 chunks of 16B
#define LDS_CHUNKS 3328           // 13 iters * 256 (tail pad, junk never read)

// round-to-nearest-even f32 -> bf16
__device__ __forceinline__ unsigned short f2bf(float f){
  union{float f; unsigned u;} v; v.f=f;
  return (unsigned short)((v.u + 0x7FFFu + ((v.u>>16)&1u))>>16);
}

// ---------------- zero halo borders: enumerate border pixels only ----------------
#define PERSLAB (2*PIX2 + 81*260)   // 29772 border pixels per slab
__global__ void zero_border(unsigned short* __restrict__ ws){
  int idx=blockIdx.x*256+threadIdx.x;
  if(idx>=8*PERSLAB) return;
  int slab=idx/PERSLAB;
  int r=idx-slab*PERSLAB;
  int p,y,x;
  if(r<2*PIX2){
    p=(r<PIX2)?0:(P2-1);
    int rr=(r<PIX2)?r:(r-PIX2);
    y=rr/X2; x=rr-y*X2;
  }else{
    int rr=r-2*PIX2;
    p=1+rr/260;
    int q=rr%260;
    if(q<66){ y=0; x=q; }
    else if(q<132){ y=Y2-1; x=q-66; }
    else { int t=q-132; y=1+(t>>1); x=(t&1)*(X2-1); }
  }
  long pix=(long)p*PIX2+(long)y*X2+x;
  uint4 z={0u,0u,0u,0u};
  uint4* dst=(uint4*)(ws+(long)slab*SLABE+pix*16);
  dst[0]=z; dst[1]=z;
}

// ---------------- correlation + leaky relu -> bf16 NHWC padded ----------------
// grid (64 y, 8 bd, 3 iseg), block (64,4): tx = x (wave = 64 x), ty = g-quad.
// Per i-row: load each lane's own x2[yy][x] for 32 ch (96 loads total), then
// produce the 9 j-shifts via ds_bpermute (x+sh held by lane x+sh). OOB -> 0.
__global__ __launch_bounds__(256) void corr_kernel(
    const float* __restrict__ x1, const float* __restrict__ x2,
    unsigned short* __restrict__ ws)
{
  const int x=threadIdx.x, ty=threadIdx.y;
  const int y=blockIdx.x;
  const int bd=blockIdx.y, b=bd&1, d=bd>>1;
  const int dil=1<<d;                    // 1,2,4,8
  const int i0=blockIdx.z*3;
  const int g0=ty*4;
  const float* x1b = x1 + (long)b*128*4096;
  const float* x2b = x2 + (long)b*128*4096;
  float a1[8][4];
#pragma unroll
  for(int k=0;k<8;++k)
#pragma unroll
    for(int c=0;c<4;++c)
      a1[k][c]=x1b[(long)(k*16+g0+c)*4096 + y*64 + x];   // channel = k*16 + g0+c
  unsigned short* sp = ws + (long)bd*SLABE;
  for(int i=i0;i<i0+3;++i){
    const int yy=y+(i-4)*dil;
    const bool yok=(unsigned)yy<64u;
    float rv[8][4];
    if(yok){
#pragma unroll
      for(int k=0;k<8;++k)
#pragma unroll
        for(int c=0;c<4;++c)
          rv[k][c]=x2b[(long)(k*16+g0+c)*4096 + yy*64 + x];
    }else{
#pragma unroll
      for(int k=0;k<8;++k)
#pragma unroll
        for(int c=0;c<4;++c) rv[k][c]=0.f;
    }
#pragma unroll
    for(int j=0;j<9;++j){
      const int xx=x+(j-4)*dil;
      const bool ok=yok&&((unsigned)xx<64u);
      const int addr=(xx&63)*4;
      float p0=0.f,p1=0.f,p2v=0.f,p3=0.f;
#pragma unroll
      for(int k=0;k<8;++k){
        union{float f;int i;} u0,u1,u2,u3;
        u0.i=__builtin_amdgcn_ds_bpermute(addr,__float_as_int(rv[k][0]));
        u1.i=__builtin_amdgcn_ds_bpermute(addr,__float_as_int(rv[k][1]));
        u2.i=__builtin_amdgcn_ds_bpermute(addr,__float_as_int(rv[k][2]));
        u3.i=__builtin_amdgcn_ds_bpermute(addr,__float_as_int(rv[k][3]));
        p0=fmaf(a1[k][0],u0.f,p0);
        p1=fmaf(a1[k][1],u1.f,p1);
        p2v=fmaf(a1[k][2],u2.f,p2v);
        p3=fmaf(a1[k][3],u3.f,p3);
      }
      float s0=ok?p0:0.f, s1=ok?p1:0.f, s2=ok?p2v:0.f, s3=ok?p3:0.f;
      ushort4 o;
      o.x=f2bf(s0>0.f?s0:0.1f*s0);
      o.y=f2bf(s1>0.f?s1:0.1f*s1);
      o.z=f2bf(s2>0.f?s2:0.1f*s2);
      o.w=f2bf(s3>0.f?s3:0.1f*s3);
      const int p=i*9+j;
      const long pix=(long)(p+1)*PIX2+(long)(y+1)*X2+(x+1);
      *(ushort4*)(sp+pix*16+g0)=o;
    }
  }
}

// ---------------- conv3d as implicit GEMM on MFMA + bias/BN/ReLU ----------------
// grid (27 ptile, 22 ytile, 8 bd), block 256 (4 waves = x-quarters).
// Out tile: 3p x 3y x 64x x 16ch. A tile [5 pp][5 yy][66 xx][16 gi] bf16,
// LINEAR LDS (A-reads are 1024B-contiguous per wave-op -> conflict-free),
// staged via 13x global_load_lds w16. Weights: global -> VGPR direct (no LDS
// writes at all). One barrier total. 53.2KB LDS -> 3 WGs/CU.
__global__ __launch_bounds__(256,3) void conv_mfma(
    const unsigned short* __restrict__ ws,
    const float* __restrict__ w_all, const float* __restrict__ bias_all,
    const float* __restrict__ gamma_all, const float* __restrict__ beta_all,
    const float* __restrict__ mean_all, const float* __restrict__ var_all,
    float* __restrict__ out)
{
  __shared__ uint4 smem4[LDS_CHUNKS];
  const int tid=threadIdx.x, lane=tid&63, wv=tid>>6;
  const int bz=blockIdx.z, d=bz>>1, b=bz&1;
  const int p0o=blockIdx.x*3;
  const int y0o=(blockIdx.y<21)?blockIdx.y*3:61;     // last tile overlaps (same values)
  const unsigned short* slab=ws+(long)bz*SLABE;
  char* smemb=(char*)smem4;

  // 1) stage A tile: 13 iters, linear chunk c -> LDS c*16; source decoded from c
#pragma unroll
  for(int it=0; it<13; ++it){
    int c=it*256+tid;
    int cc=c>TCHUNK-1?TCHUNK-1:c;        // tail clamp (dup src; dest lane-linear in pad)
    int tp=cc>>1, half=cc&1;
    int pp=tp/TROW, rem=tp-pp*TROW;
    int yy=rem/66, xx=rem-yy*66;
    const char* gp=(const char*)slab
      + ((long)(p0o+pp)*PIX2+(long)(y0o+yy)*X2+xx)*32 + half*16;
    char* lp=smemb+((it*256+(tid&~63)))*16;          // wave-uniform base + lane*16
    __builtin_amdgcn_global_load_lds(
      (const __attribute__((address_space(1))) void*)gp,
      (__attribute__((address_space(3))) void*)lp, 16, 0, 0);
  }

  // 2) weights -> VGPR direct (overlaps staging flight), zero-pad taps 27..31
  const int n=lane&15, kg=lane>>4, chunk=kg&1, hi=kg>>1;
  const float* wd=w_all+(long)d*16*16*27;            // [go][gi][tap]
  const int gi0=(kg&1)*8;
  short8v bfr[14];
#pragma unroll
  for(int s=0;s<14;++s){
    const int tap=2*s+hi;
    union{unsigned short h[8]; short8v v;} u;
    if(tap<27){
#pragma unroll
      for(int e=0;e<8;++e) u.h[e]=f2bf(wd[(n*16+gi0+e)*27+tap]);
    }else{
#pragma unroll
      for(int e=0;e<8;++e) u.h[e]=0;
    }
    bfr[s]=u.v;
  }

  const float scl=gamma_all[d*16+n]*rsqrtf(var_all[d*16+n]+1e-5f);
  const float ofs=(bias_all[d*16+n]-mean_all[d*16+n])*scl+beta_all[d*16+n];

  __syncthreads();                                   // staging (and weights) complete

  // 3) K-loop: per s, 9 (p,y) reads + 9 MFMA; tap offsets compile-time
  const char* sm=(const char*)smem4;
  const int x0=wv*16;
  const int XB=(x0+n)*32+chunk*16;
  f32x4 acc[3][3];
#pragma unroll
  for(int p=0;p<3;++p)
#pragma unroll
    for(int y=0;y<3;++y) acc[p][y]=(f32x4){0,0,0,0};

#pragma unroll
  for(int s=0;s<14;++s){
    const int t0=2*s, t1=2*s+1;
    const int O0=((t0/9)*TROW+((t0%9)/3)*66+(t0%3))*32;
    const int O1=(t1<27)?(((t1/9)*TROW+((t1%9)/3)*66+(t1%3))*32):0;
    const int osel=hi?O1:O0;
#pragma unroll
    for(int p=0;p<3;++p){
#pragma unroll
      for(int y=0;y<3;++y){
        const int L=(p*TROW+y*66)*32+XB+osel;
        short8v a=*(const short8v*)(sm+L);
        acc[p][y]=__builtin_amdgcn_mfma_f32_16x16x32_bf16(a,bfr[s],acc[p][y],0,0,0);
      }
    }
  }

  // 4) epilogue: bias+BN+ReLU, store [b][d*16+n][P][Y][x]
#pragma unroll
  for(int p=0;p<3;++p){
#pragma unroll
    for(int y=0;y<3;++y){
      const int P=p0o+p, Y=y0o+y;
      float* ob=out+(((long)(b*64+d*16+n)*NP+P)*4096)+Y*64+x0+kg*4;
      f32x4 a=acc[p][y];
#pragma unroll
      for(int rr=0;rr<4;++rr){
        float vv=fmaf(a[rr],scl,ofs);
        ob[rr]=vv>0.f?vv:0.f;
      }
    }
  }
}

extern "C" void kernel_launch(void* const* d_in, const int* in_sizes, int n_in,
                              void* d_out, int out_size, void* d_ws, size_t ws_size,
                              hipStream_t stream) {
  const float* x    = (const float*)d_in[0];
  const float* nbx  = (const float*)d_in[1];
  const float* cw   = (const float*)d_in[2];
  const float* cbia = (const float*)d_in[3];
  const float* gam  = (const float*)d_in[4];
  const float* bet  = (const float*)d_in[5];
  const float* mea  = (const float*)d_in[6];
  const float* var  = (const float*)d_in[7];
  float* out = (float*)d_out;
  unsigned short* ws16 = (unsigned short*)d_ws;   // 8 slabs * 11.57 MB = 92.6 MB

  zero_border<<<dim3((8*PERSLAB+255)/256),dim3(256),0,stream>>>(ws16);
  corr_kernel<<<dim3(64,8,3),dim3(64,4),0,stream>>>(x,nbx,ws16);
  conv_mfma<<<dim3(27,22,8),dim3(256),0,stream>>>(ws16,cw,cbia,gam,bet,mea,var,out);
}